// Round 1
// 445.524 us; speedup vs baseline: 1.0623x; 1.0623x over previous
//
#include <hip/hip_runtime.h>
#include <math.h>

// Problem constants (match reference): B=65536, D_IN=1024, D_OUT=1024, 4 qubits, 1 layer.
#define D_IN_K  1024
#define D_OUT_K 1024

static constexpr float PI_F = 3.14159265358979323846f;

__device__ __forceinline__ float dot4(float4 a, float4 b, float acc) {
    return fmaf(a.x, b.x, fmaf(a.y, b.y, fmaf(a.z, b.z, fmaf(a.w, b.w, acc))));
}

// ---------------------------------------------------------------------------
// 4-qubit statevector helpers: all 16 complex amplitudes in registers,
// fully unrolled, compile-time masks.
// Index convention (matches reference reshape (b,2,2,2,2)): wire w -> bit (3-w).
// ---------------------------------------------------------------------------
template <int MASK>
__device__ __forceinline__ void apply1q(
    float* pr, float* pim,
    float u00r, float u00i, float u01r, float u01i,
    float u10r, float u10i, float u11r, float u11i)
{
#pragma unroll
    for (int j = 0; j < 16; ++j) {
        if (j & MASK) continue;
        const int k = j | MASK;
        float a0r = pr[j], a0i = pim[j], a1r = pr[k], a1i = pim[k];
        pr[j]  = u00r * a0r - u00i * a0i + u01r * a1r - u01i * a1i;
        pim[j] = u00r * a0i + u00i * a0r + u01r * a1i + u01i * a1r;
        pr[k]  = u10r * a0r - u10i * a0i + u11r * a1r - u11i * a1i;
        pim[k] = u10r * a0i + u10i * a0r + u11r * a1i + u11i * a1r;
    }
}

template <int CMASK, int TMASK>
__device__ __forceinline__ void cnot(float* pr, float* pim)
{
#pragma unroll
    for (int j = 0; j < 16; ++j) {
        if ((j & CMASK) && !(j & TMASK)) {
            const int k = j | TMASK;
            float t;
            t = pr[j];  pr[j]  = pr[k];  pr[k]  = t;
            t = pim[j]; pim[j] = pim[k]; pim[k] = t;
        }
    }
}

template <int MASK>
__device__ __forceinline__ void encode_qubit(float* pr, float* pim, float f)
{
    const float r = 0.70710678118654752440f;
    // H
    apply1q<MASK>(pr, pim, r, 0.f, r, 0.f, r, 0.f, -r, 0.f);
    // RY(arctan(f))
    float th = atanf(f) * 0.5f;
    float s, c;
    sincosf(th, &s, &c);
    apply1q<MASK>(pr, pim, c, 0.f, -s, 0.f, s, 0.f, c, 0.f);
    // RZ(arctan(f^2)) = diag(e^{-ia/2}, e^{+ia/2})
    float al = atanf(f * f) * 0.5f;
    float sa, ca;
    sincosf(al, &sa, &ca);
    apply1q<MASK>(pr, pim, ca, -sa, 0.f, 0.f, 0.f, 0.f, ca, sa);
}

template <int MASK>
__device__ __forceinline__ void rot_qubit(float* pr, float* pim,
                                          float phi, float th, float om)
{
    float st, ct, sp, cp, sm, cm;
    sincosf(0.5f * th, &st, &ct);
    sincosf(0.5f * (phi + om), &sp, &cp);
    sincosf(0.5f * (phi - om), &sm, &cm);
    apply1q<MASK>(pr, pim,
                  ct * cp, -ct * sp,
                  -st * cm, -st * sm,
                  st * cm, -st * sm,
                  ct * cp, ct * sp);
}

// ---------------------------------------------------------------------------
// Fully fused kernel: 16 rows per 256-thread block.
//  Phase 1 (pre): wave w owns rows row0+4w..+3. 4 rows/wave GEMV over D_IN
//    with float4 loads; butterfly all-reduce leaves ALL 16 (row,q) sums in
//    every lane of the wave.
//  Phase 2 (circuit): lanes 0..3 of each wave run the 4-qubit statevector
//    for one row each, entirely in registers; z (4 floats) -> 256B of LDS.
//  Phase 3 (post): all 256 threads, thread t owns out columns {t,t+256,
//    t+512,t+768}; post_w loaded once per block (issued at kernel start so
//    the load is in flight under phase 1); z read is a uniform LDS broadcast.
// h and z never touch global memory -> d_ws is completely unused (the 1-GiB
// workspace re-poison fills dominate the current timing).
// ---------------------------------------------------------------------------
__global__ __launch_bounds__(256) void fused_kernel(
    const float* __restrict__ x, const float* __restrict__ pw,
    const float* __restrict__ pb, const float* __restrict__ qw,
    const float* __restrict__ postw, const float* __restrict__ postb,
    float* __restrict__ out, int B)
{
    const int t    = threadIdx.x;
    const int wave = t >> 6;
    const int lane = t & 63;
    const int row0  = blockIdx.x * 16;        // block's first row
    const int wrow0 = row0 + wave * 4;        // wave's first row
    if (row0 >= B) return;

    __shared__ float4 zlds[16];

    // ---- Issue phase-3 weight loads early (held in regs across phases) ----
    const float4* pwv4 = reinterpret_cast<const float4*>(postw);
    float4 w[4];
    float bias[4];
#pragma unroll
    for (int j = 0; j < 4; ++j) {
        w[j]    = pwv4[t + 256 * j];
        bias[j] = postb[t + 256 * j];
    }

    // ---- Phase 1: pre GEMV, 4 rows per wave --------------------------------
    const float4* w0 = reinterpret_cast<const float4*>(pw);
    const float4* w1 = reinterpret_cast<const float4*>(pw + D_IN_K);
    const float4* w2 = reinterpret_cast<const float4*>(pw + 2 * D_IN_K);
    const float4* w3 = reinterpret_cast<const float4*>(pw + 3 * D_IN_K);
    const float4* x0 = reinterpret_cast<const float4*>(x + (size_t)(wrow0 + 0) * D_IN_K);
    const float4* x1 = reinterpret_cast<const float4*>(x + (size_t)(wrow0 + 1) * D_IN_K);
    const float4* x2 = reinterpret_cast<const float4*>(x + (size_t)(wrow0 + 2) * D_IN_K);
    const float4* x3 = reinterpret_cast<const float4*>(x + (size_t)(wrow0 + 3) * D_IN_K);

    float acc[4][4];
#pragma unroll
    for (int r = 0; r < 4; ++r)
#pragma unroll
        for (int q = 0; q < 4; ++q) acc[r][q] = 0.f;

#pragma unroll
    for (int k = 0; k < 4; ++k) {
        const int idx = lane + (k << 6);          // float4 index 0..255
        float4 a = w0[idx], b = w1[idx], c = w2[idx], d = w3[idx];
        float4 xv;
        xv = x0[idx];
        acc[0][0] = dot4(xv, a, acc[0][0]); acc[0][1] = dot4(xv, b, acc[0][1]);
        acc[0][2] = dot4(xv, c, acc[0][2]); acc[0][3] = dot4(xv, d, acc[0][3]);
        xv = x1[idx];
        acc[1][0] = dot4(xv, a, acc[1][0]); acc[1][1] = dot4(xv, b, acc[1][1]);
        acc[1][2] = dot4(xv, c, acc[1][2]); acc[1][3] = dot4(xv, d, acc[1][3]);
        xv = x2[idx];
        acc[2][0] = dot4(xv, a, acc[2][0]); acc[2][1] = dot4(xv, b, acc[2][1]);
        acc[2][2] = dot4(xv, c, acc[2][2]); acc[2][3] = dot4(xv, d, acc[2][3]);
        xv = x3[idx];
        acc[3][0] = dot4(xv, a, acc[3][0]); acc[3][1] = dot4(xv, b, acc[3][1]);
        acc[3][2] = dot4(xv, c, acc[3][2]); acc[3][3] = dot4(xv, d, acc[3][3]);
    }

    // Butterfly all-reduce: EVERY lane ends with all 16 full (row,q) sums.
#pragma unroll
    for (int off = 1; off < 64; off <<= 1) {
#pragma unroll
        for (int r = 0; r < 4; ++r)
#pragma unroll
            for (int q = 0; q < 4; ++q)
                acc[r][q] += __shfl_xor(acc[r][q], off, 64);
    }

    // ---- Phase 2: circuit, lanes 0..3 of each wave, one row each -----------
    if (lane < 4) {
        const int r = lane;                       // local row within wave
        float hq[4];
#pragma unroll
        for (int q = 0; q < 4; ++q)
            hq[q] = tanhf(acc[r][q] + pb[q]) * PI_F;

        float pr[16], pim[16];
#pragma unroll
        for (int j = 0; j < 16; ++j) { pr[j] = 0.f; pim[j] = 0.f; }
        pr[0] = 1.f;

        encode_qubit<8>(pr, pim, hq[0]);
        encode_qubit<4>(pr, pim, hq[1]);
        encode_qubit<2>(pr, pim, hq[2]);
        encode_qubit<1>(pr, pim, hq[3]);

        cnot<8, 4>(pr, pim);
        cnot<4, 2>(pr, pim);
        cnot<2, 1>(pr, pim);
        cnot<1, 8>(pr, pim);

        rot_qubit<8>(pr, pim, qw[0], qw[1], qw[2]);
        rot_qubit<4>(pr, pim, qw[3], qw[4], qw[5]);
        rot_qubit<2>(pr, pim, qw[6], qw[7], qw[8]);
        rot_qubit<1>(pr, pim, qw[9], qw[10], qw[11]);

        float z0 = 0.f, z1 = 0.f, z2 = 0.f, z3 = 0.f;
#pragma unroll
        for (int j = 0; j < 16; ++j) {
            float p = pr[j] * pr[j] + pim[j] * pim[j];
            z0 += (j & 8) ? -p : p;
            z1 += (j & 4) ? -p : p;
            z2 += (j & 2) ? -p : p;
            z3 += (j & 1) ? -p : p;
        }
        float4 zv; zv.x = z0; zv.y = z1; zv.z = z2; zv.w = z3;
        zlds[wave * 4 + r] = zv;
    }
    __syncthreads();

    // ---- Phase 3: post GEMV, all 256 threads, 16 rows ----------------------
#pragma unroll
    for (int r = 0; r < 16; ++r) {
        float4 zr = zlds[r];                      // uniform broadcast read
        float* orow = out + (size_t)(row0 + r) * D_OUT_K;
#pragma unroll
        for (int j = 0; j < 4; ++j) {
            float o = fmaf(zr.x, w[j].x,
                      fmaf(zr.y, w[j].y,
                      fmaf(zr.z, w[j].z,
                      fmaf(zr.w, w[j].w, bias[j]))));
            orow[t + 256 * j] = o;
        }
    }
}

// ---------------------------------------------------------------------------
extern "C" void kernel_launch(void* const* d_in, const int* in_sizes, int n_in,
                              void* d_out, int out_size, void* d_ws, size_t ws_size,
                              hipStream_t stream)
{
    const float* x      = (const float*)d_in[0];  // (B, 1024)
    const float* pre_w  = (const float*)d_in[1];  // (4, 1024)
    const float* pre_b  = (const float*)d_in[2];  // (4,)
    const float* qw     = (const float*)d_in[3];  // (1, 4, 3)
    const float* post_w = (const float*)d_in[4];  // (1024, 4)
    const float* post_b = (const float*)d_in[5];  // (1024,)
    float* out = (float*)d_out;                   // (B, 1024) fp32

    const int B = in_sizes[0] / D_IN_K;           // 65536

    // d_ws intentionally unused: h and z live in registers/LDS inside the
    // fused kernel, so the harness's 1-GiB workspace never enters our path.
    (void)d_ws; (void)ws_size;

    fused_kernel<<<(B + 15) / 16, 256, 0, stream>>>(
        x, pre_w, pre_b, qw, post_w, post_b, out, B);
}